// Round 8
// baseline (362.073 us; speedup 1.0000x reference)
//
#include <hip/hip_runtime.h>
#include <hip/hip_bf16.h>
#include <cstdint>

#define DI __device__ __forceinline__

typedef __attribute__((ext_vector_type(4))) float f32x4;
typedef __attribute__((ext_vector_type(8))) short bf16x8;

static constexpr int B_ = 16384, I_ = 1024, H_ = 1024;
static constexpr int M = B_;          // 16384 rows
static constexpr int N = 4 * H_;      // 4096 gate-cols (permuted: see cvt)
static constexpr int K = I_ + H_;     // 2048 ([x | h])
static constexpr int NT = K / 64;     // 32 K-tiles

// workspace layout (bytes)
static constexpr size_t OFF_A  = 0;                         // M*K bf16   (64 MB)
static constexpr size_t OFF_W  = OFF_A + (size_t)M * K * 2; // N*K bf16   (16 MB)
static constexpr size_t OFF_BI = OFF_W + (size_t)N * K * 2; // N f32      (16 KB)

DI unsigned short f2bf(float f) {
    union { float f; unsigned u; } v; v.f = f;
    unsigned r = v.u + 0x7FFFu + ((v.u >> 16) & 1u);
    return (unsigned short)(r >> 16);
}

// ---------------------------------------------------------------- convert
// A' = [x | h] (M x K) bf16. W' rows PERMUTED so that GEMM col
// r = g64*64 + gate*16 + l15 maps to (gate, hcol = g64*16 + l15).
__global__ void cvt_kernel(const float* __restrict__ x, const float* __restrict__ h,
                           const float* __restrict__ Wx, const float* __restrict__ Wh,
                           unsigned short* __restrict__ A, unsigned short* __restrict__ W)
{
    long tid = (long)blockIdx.x * blockDim.x + threadIdx.x;
    long row = tid >> 9;
    int  col = (int)(tid & 511) * 4;
    const float* src;
    unsigned short* dst;
    if (row < M) {
        src = (col < I_) ? x + (size_t)row * I_ + col
                         : h + (size_t)row * H_ + (col - I_);
        dst = A + (size_t)row * K + col;
    } else {
        int r = (int)(row - M);                 // dst row in W'
        int gate = (r >> 4) & 3;
        int hcol = ((r >> 6) << 4) | (r & 15);
        int srow = gate * H_ + hcol;            // src row in [4,H] stack
        src = (col < I_) ? Wx + (size_t)srow * I_ + col
                         : Wh + (size_t)srow * H_ + (col - I_);
        dst = W + (size_t)r * K + col;
    }
    float4 v = *(const float4*)src;
    ushort4 o;
    o.x = f2bf(v.x); o.y = f2bf(v.y); o.z = f2bf(v.z); o.w = f2bf(v.w);
    *(ushort4*)dst = o;
}

__global__ void bias_kernel(const float* __restrict__ bx, const float* __restrict__ bh,
                            float* __restrict__ bias)
{
    int r = blockIdx.x * blockDim.x + threadIdx.x;
    if (r < N) {
        int gate = (r >> 4) & 3;
        int hcol = ((r >> 6) << 4) | (r & 15);
        int s = gate * H_ + hcol;
        bias[r] = bx[s] + bh[s];
    }
}

// ---------------------------------------------------------------- GEMM 256x256
// 1024 threads = 16 waves in a 4x4 grid, 64x64 per wave. acc = 64 VGPR ->
// total regs <= 128 (enforced by launch bounds) -> 16 waves/CU (4/SIMD),
// double the previous occupancy. Whole tile t+1 staged in P1 (target buffer
// provably idle since P4(t-1) trailing barrier); single vmcnt(0) at P4
// pre-barrier (3 phases after issue; publishes all waves' stages before any
// wave crosses into tile t+1 -- the round-5 correctness invariant).
DI void stage_half16(const unsigned short* __restrict__ g, int grow0, int kcol,
                     unsigned short* ldsbase, int tid)
{
    const int w    = tid >> 6;                 // 0..15
    const int lane = tid & 63;
    const int rsub = (w << 3) + (lane >> 3);   // 0..127
    const int kk   = kcol + (((lane & 7) ^ (lane >> 3)) << 3);  // inverse-swizzled src
    const unsigned short* gp = g + (size_t)(grow0 + rsub) * K + kk;
    unsigned short* lp = ldsbase + ((w << 3) << 6);             // wave-uniform
    __builtin_amdgcn_global_load_lds(
        (const __attribute__((address_space(1))) void*)gp,
        (__attribute__((address_space(3))) void*)lp, 16, 0, 0);
}

DI bf16x8 ldfrag(const unsigned short* tile, int row, int ks, int lane)
{
    const int sl = ((ks << 2) + (lane >> 4)) ^ (lane & 7);      // row&7 == lane&7
    return *(const bf16x8*)(tile + (row << 6) + (sl << 3));
}

DI float sigf(float v) { return 1.f / (1.f + __expf(-v)); }
DI float tanhfast(float v) {
    float vc = fminf(fmaxf(v, -15.f), 15.f);
    float e  = __expf(2.f * vc);
    return (e - 1.f) / (e + 1.f);
}

// phase tail: barrier, LDS drain, prioritized 8-MFMA cluster, barrier
#define PHASE_MFMA8(M0)                                                       \
    __builtin_amdgcn_s_barrier();                                             \
    asm volatile("s_waitcnt lgkmcnt(0)");                                     \
    __builtin_amdgcn_s_setprio(1);                                            \
    _Pragma("unroll") for (int n_ = 0; n_ < 4; ++n_)                          \
        acc[M0][n_] = __builtin_amdgcn_mfma_f32_16x16x32_bf16(                \
            a2[0], b4[n_], acc[M0][n_], 0, 0, 0);                             \
    _Pragma("unroll") for (int n_ = 0; n_ < 4; ++n_)                          \
        acc[(M0) + 1][n_] = __builtin_amdgcn_mfma_f32_16x16x32_bf16(          \
            a2[1], b4[n_], acc[(M0) + 1][n_], 0, 0, 0);                       \
    __builtin_amdgcn_s_setprio(0);                                            \
    __builtin_amdgcn_s_barrier();

__global__ __launch_bounds__(1024, 4) void gemm_lstm(
    const unsigned short* __restrict__ Abf, const unsigned short* __restrict__ Wbf,
    const float* __restrict__ bias, const float* __restrict__ c,
    float* __restrict__ out)
{
    __shared__ __align__(16) unsigned short sh[65536];   // 128 KiB

    const int tid  = threadIdx.x;
    const int lane = tid & 63;
    const int wid  = tid >> 6;            // 0..15
    const int wr   = wid >> 2;            // 0..3
    const int wc   = wid & 3;             // 0..3

    const int bid  = blockIdx.x;
    const int wg   = ((bid & 7) << 7) | (bid >> 3);   // XCD swizzle (1024%8==0)
    const int nbk  = wg & 15, mbk = wg >> 4;
    const int brow = mbk << 8, bcol = nbk << 8;

    const int l15  = lane & 15;
    const int rA0  = (wr << 6) + l15;     // + m*16, m=0..3
    const int rB0  = (wc << 6) + l15;     // + n*16, n=0..3

    f32x4 acc[4][4];
#pragma unroll
    for (int i = 0; i < 4; ++i)
#pragma unroll
        for (int j = 0; j < 4; ++j) acc[i][j] = f32x4{0.f, 0.f, 0.f, 0.f};
    bf16x8 a2[2], b4[4];

    // prologue: stage tile0 (4 loads), drain, barrier
    {
        stage_half16(Abf, brow,       0, sh,         tid);
        stage_half16(Abf, brow + 128, 0, sh + 8192,  tid);
        stage_half16(Wbf, bcol,       0, sh + 16384, tid);
        stage_half16(Wbf, bcol + 128, 0, sh + 24576, tid);
        asm volatile("s_waitcnt vmcnt(0)" ::: "memory");
        __builtin_amdgcn_s_barrier();
    }

    for (int t = 0; t < NT; ++t) {
        const int q = t & 1;
        unsigned short* curA = sh + q * 32768;
        unsigned short* curB = curA + 16384;
        unsigned short* nxtA = sh + (q ^ 1) * 32768;
        unsigned short* nxtB = nxtA + 16384;
        const int k1 = (t + 1) << 6;

        // ---- P1: stage entire tile t+1 (nxt buffer idle since P4(t-1));
        // read ks0 frags (a m0,m1 + b n0-3); MFMA m0,m1 x n0-3 @ ks0
        if (t + 1 < NT) {
            stage_half16(Abf, brow,       k1, nxtA,        tid);
            stage_half16(Abf, brow + 128, k1, nxtA + 8192, tid);
            stage_half16(Wbf, bcol,       k1, nxtB,        tid);
            stage_half16(Wbf, bcol + 128, k1, nxtB + 8192, tid);
        }
        a2[0] = ldfrag(curA, rA0,      0, lane);
        a2[1] = ldfrag(curA, rA0 + 16, 0, lane);
#pragma unroll
        for (int n = 0; n < 4; ++n) b4[n] = ldfrag(curB, rB0 + n * 16, 0, lane);
        PHASE_MFMA8(0);

        // ---- P2: read a m2,m3 @ ks0; MFMA m2,m3 x n0-3 @ ks0
        a2[0] = ldfrag(curA, rA0 + 32, 0, lane);
        a2[1] = ldfrag(curA, rA0 + 48, 0, lane);
        PHASE_MFMA8(2);

        // ---- P3: read ks1 frags (a m0,m1 + b n0-3); MFMA m0,m1 @ ks1
        a2[0] = ldfrag(curA, rA0,      1, lane);
        a2[1] = ldfrag(curA, rA0 + 16, 1, lane);
#pragma unroll
        for (int n = 0; n < 4; ++n) b4[n] = ldfrag(curB, rB0 + n * 16, 1, lane);
        PHASE_MFMA8(0);

        // ---- P4: read a m2,m3 @ ks1; vmcnt(0) pre-barrier (stages issued
        // 3 phases ago -> cheap; publishes tile t+1 for all waves); MFMA
        a2[0] = ldfrag(curA, rA0 + 32, 1, lane);
        a2[1] = ldfrag(curA, rA0 + 48, 1, lane);
        asm volatile("s_waitcnt vmcnt(0)" ::: "memory");
        PHASE_MFMA8(2);
    }

    // ---- fused LSTM epilogue: n-index = gate for one h-col per lane
    const int hcol  = (((nbk << 2) + wc) << 4) + l15;
    const int crow0 = brow + (wr << 6) + ((lane >> 4) << 2);
    const int cb0   = bcol + (wc << 6) + l15;
    const float bs0 = bias[cb0];
    const float bs1 = bias[cb0 + 16];
    const float bs2 = bias[cb0 + 32];
    const float bs3 = bias[cb0 + 48];
    const size_t P  = (size_t)B_ * H_;
#pragma unroll
    for (int mf = 0; mf < 4; ++mf) {
#pragma unroll
        for (int j = 0; j < 4; ++j) {
            const int row = crow0 + mf * 16 + j;
            const size_t base = (size_t)row * H_ + hcol;
            float fg = sigf(acc[mf][0][j] + bs0);
            float ig = sigf(acc[mf][1][j] + bs1);
            float kg = tanhfast(acc[mf][2][j] + bs2);
            float og = sigf(acc[mf][3][j] + bs3);
            float cv = c[base];
            float cn = fg * cv + ig * kg;
            float hn = og * tanhfast(cn);
            out[base]         = og;
            out[P + base]     = cn;
            out[2 * P + base] = hn;
        }
    }
}

// ---------------------------------------------------------------- launch
extern "C" void kernel_launch(void* const* d_in, const int* in_sizes, int n_in,
                              void* d_out, int out_size, void* d_ws, size_t ws_size,
                              hipStream_t stream)
{
    const float* x  = (const float*)d_in[0];
    const float* c  = (const float*)d_in[1];
    const float* h  = (const float*)d_in[2];
    const float* Wx = (const float*)d_in[3];
    const float* bx = (const float*)d_in[4];
    const float* Wh = (const float*)d_in[5];
    const float* bh = (const float*)d_in[6];

    unsigned short* Abf  = (unsigned short*)((char*)d_ws + OFF_A);
    unsigned short* Wbf  = (unsigned short*)((char*)d_ws + OFF_W);
    float*          bias = (float*)((char*)d_ws + OFF_BI);
    float*          out  = (float*)d_out;

    cvt_kernel<<<40960, 256, 0, stream>>>(x, h, Wx, Wh, Abf, Wbf);
    bias_kernel<<<16, 256, 0, stream>>>(bx, bh, bias);
    gemm_lstm<<<(M / 256) * (N / 256), 1024, 0, stream>>>(
        Abf, Wbf, bias, c, out);
}

// Round 9
// 335.511 us; speedup vs baseline: 1.0792x; 1.0792x over previous
//
#include <hip/hip_runtime.h>
#include <hip/hip_bf16.h>
#include <cstdint>

#define DI __device__ __forceinline__

typedef __attribute__((ext_vector_type(4))) float f32x4;
typedef __attribute__((ext_vector_type(8))) short bf16x8;

static constexpr int B_ = 16384, I_ = 1024, H_ = 1024;
static constexpr int M = B_;          // 16384 rows
static constexpr int N = 4 * H_;      // 4096 gate-cols (permuted: see cvt)
static constexpr int K = I_ + H_;     // 2048 ([x | h])
static constexpr int NT = K / 64;     // 32 K-tiles

// workspace layout (bytes)
static constexpr size_t OFF_A  = 0;                         // M*K bf16   (64 MB)
static constexpr size_t OFF_W  = OFF_A + (size_t)M * K * 2; // N*K bf16   (16 MB)
static constexpr size_t OFF_BI = OFF_W + (size_t)N * K * 2; // N f32      (16 KB)

DI unsigned short f2bf(float f) {
    union { float f; unsigned u; } v; v.f = f;
    unsigned r = v.u + 0x7FFFu + ((v.u >> 16) & 1u);
    return (unsigned short)(r >> 16);
}

// ---------------------------------------------------------------- convert
// A' = [x | h] (M x K) bf16. W' rows PERMUTED so that GEMM col
// r = g64*64 + gate*16 + l15 maps to (gate, hcol = g64*16 + l15).
__global__ void cvt_kernel(const float* __restrict__ x, const float* __restrict__ h,
                           const float* __restrict__ Wx, const float* __restrict__ Wh,
                           unsigned short* __restrict__ A, unsigned short* __restrict__ W)
{
    long tid = (long)blockIdx.x * blockDim.x + threadIdx.x;
    long row = tid >> 9;
    int  col = (int)(tid & 511) * 4;
    const float* src;
    unsigned short* dst;
    if (row < M) {
        src = (col < I_) ? x + (size_t)row * I_ + col
                         : h + (size_t)row * H_ + (col - I_);
        dst = A + (size_t)row * K + col;
    } else {
        int r = (int)(row - M);                 // dst row in W'
        int gate = (r >> 4) & 3;
        int hcol = ((r >> 6) << 4) | (r & 15);
        int srow = gate * H_ + hcol;            // src row in [4,H] stack
        src = (col < I_) ? Wx + (size_t)srow * I_ + col
                         : Wh + (size_t)srow * H_ + (col - I_);
        dst = W + (size_t)r * K + col;
    }
    float4 v = *(const float4*)src;
    ushort4 o;
    o.x = f2bf(v.x); o.y = f2bf(v.y); o.z = f2bf(v.z); o.w = f2bf(v.w);
    *(ushort4*)dst = o;
}

__global__ void bias_kernel(const float* __restrict__ bx, const float* __restrict__ bh,
                            float* __restrict__ bias)
{
    int r = blockIdx.x * blockDim.x + threadIdx.x;
    if (r < N) {
        int gate = (r >> 4) & 3;
        int hcol = ((r >> 6) << 4) | (r & 15);
        int s = gate * H_ + hcol;
        bias[r] = bx[s] + bh[s];
    }
}

// ---------------------------------------------------------------- GEMM 256x256
// ONE barrier per K-tile; tile body is compiler-scheduled (no sched_barrier,
// no setprio, no intra-tile barriers) so ds_read issue overlaps MFMA issue.
// Correctness: (1) each wave's ds_reads of cur complete before its consuming
// MFMAs (compiler-inserted counted lgkmcnt), which precede the tile-end
// barrier -> after the barrier cur may be overwritten; (2) stages for t+1
// issued at tile start target the opposite buffer; tile-end vmcnt(0)
// (issued ~a full tile earlier, no stall) + barrier publishes them to all
// waves before tile t+1 reads -- the round-5 invariant.
DI void stage_half(const unsigned short* __restrict__ g, int grow0, int kcol,
                   unsigned short* ldsbase, int tid)
{
    const int w    = tid >> 6, lane = tid & 63;
    const int rsub = (w << 3) + (lane >> 3);
    const int kk   = kcol + (((lane & 7) ^ (lane >> 3)) << 3);  // inverse-swizzled src
#pragma unroll
    for (int l = 0; l < 2; ++l) {
        const unsigned short* gp = g + (size_t)(grow0 + (l << 6) + rsub) * K + kk;
        unsigned short* lp = ldsbase + (((l << 6) + (w << 3)) << 6);
        __builtin_amdgcn_global_load_lds(
            (const __attribute__((address_space(1))) void*)gp,
            (__attribute__((address_space(3))) void*)lp, 16, 0, 0);
    }
}

DI bf16x8 ldfrag(const unsigned short* tile, int row, int ks, int lane)
{
    const int sl = ((ks << 2) + (lane >> 4)) ^ (lane & 7);
    return *(const bf16x8*)(tile + (row << 6) + (sl << 3));
}

DI float sigf(float v) { return 1.f / (1.f + __expf(-v)); }
DI float tanhfast(float v) {
    float vc = fminf(fmaxf(v, -15.f), 15.f);
    float e  = __expf(2.f * vc);
    return (e - 1.f) / (e + 1.f);
}

__global__ __launch_bounds__(512, 2) void gemm_lstm(
    const unsigned short* __restrict__ Abf, const unsigned short* __restrict__ Wbf,
    const float* __restrict__ bias, const float* __restrict__ c,
    float* __restrict__ out)
{
    __shared__ __align__(16) unsigned short sh[65536];   // 128 KiB

    const int tid  = threadIdx.x;
    const int lane = tid & 63;
    const int wid  = tid >> 6;
    const int wr   = wid >> 2;            // 0..1
    const int wc   = wid & 3;             // 0..3

    const int bid  = blockIdx.x;
    const int wg   = ((bid & 7) << 7) | (bid >> 3);   // XCD swizzle (1024%8==0)
    const int nbk  = wg & 15, mbk = wg >> 4;
    const int brow = mbk << 8, bcol = nbk << 8;

    const int l15  = lane & 15;
    const int rA0  = (wr << 7) + l15;
    const int rB0  = (wc << 6) + l15;

    f32x4 acc[8][4];
#pragma unroll
    for (int i = 0; i < 8; ++i)
#pragma unroll
        for (int j = 0; j < 4; ++j) acc[i][j] = f32x4{0.f, 0.f, 0.f, 0.f};
    bf16x8 a[4][2], b[4][2];

    // prologue: stage tile0, drain, publish
    {
        stage_half(Abf, brow,       0, sh,         tid);
        stage_half(Abf, brow + 128, 0, sh + 8192,  tid);
        stage_half(Wbf, bcol,       0, sh + 16384, tid);
        stage_half(Wbf, bcol + 128, 0, sh + 24576, tid);
        asm volatile("s_waitcnt vmcnt(0)" ::: "memory");
        __builtin_amdgcn_s_barrier();
    }

    for (int t = 0; t < NT; ++t) {
        const int q = t & 1;
        unsigned short* curA = sh + q * 32768;
        unsigned short* curB = curA + 16384;
        unsigned short* nxtA = sh + (q ^ 1) * 32768;
        unsigned short* nxtB = nxtA + 16384;
        const int k1 = ((t + 1) & 31) << 6;   // wrapped at tail: garbage into dead buf

        // stage entire tile t+1 (4 VM ops; nxt was last read in tile t-1,
        // all reads done before the (t-1)-end barrier)
        stage_half(Abf, brow,       k1, nxtA,        tid);
        stage_half(Abf, brow + 128, k1, nxtA + 8192, tid);
        stage_half(Wbf, bcol,       k1, nxtB,        tid);
        stage_half(Wbf, bcol + 128, k1, nxtB + 8192, tid);

        // ---- B frags (8 reads) + A mh0 (8 reads)
#pragma unroll
        for (int n = 0; n < 4; ++n)
#pragma unroll
            for (int ks = 0; ks < 2; ++ks)
                b[n][ks] = ldfrag(curB, rB0 + n * 16, ks, lane);
#pragma unroll
        for (int m = 0; m < 4; ++m)
#pragma unroll
            for (int ks = 0; ks < 2; ++ks)
                a[m][ks] = ldfrag(curA, rA0 + m * 16, ks, lane);

        // ---- MFMA mh0 (32): compiler inserts counted lgkmcnt as needed
#pragma unroll
        for (int ks = 0; ks < 2; ++ks)
#pragma unroll
            for (int m = 0; m < 4; ++m)
#pragma unroll
                for (int n = 0; n < 4; ++n)
                    acc[m][n] = __builtin_amdgcn_mfma_f32_16x16x32_bf16(
                        a[m][ks], b[n][ks], acc[m][n], 0, 0, 0);

        // ---- A mh1 (8 reads, reuse a[] regs)
#pragma unroll
        for (int m = 0; m < 4; ++m)
#pragma unroll
            for (int ks = 0; ks < 2; ++ks)
                a[m][ks] = ldfrag(curA, rA0 + 64 + m * 16, ks, lane);

        // ---- MFMA mh1 (32)
#pragma unroll
        for (int ks = 0; ks < 2; ++ks)
#pragma unroll
            for (int m = 0; m < 4; ++m)
#pragma unroll
                for (int n = 0; n < 4; ++n)
                    acc[4 + m][n] = __builtin_amdgcn_mfma_f32_16x16x32_bf16(
                        a[m][ks], b[n][ks], acc[4 + m][n], 0, 0, 0);

        // tile-end: publish tile t+1 (stages issued ~full tile ago -> no
        // stall) and release cur for overwriting
        asm volatile("s_waitcnt vmcnt(0)" ::: "memory");
        __builtin_amdgcn_s_barrier();
    }

    // ---- fused LSTM epilogue: n-index = gate for one h-col per lane
    const int hcol  = (((nbk << 2) + wc) << 4) + l15;
    const int crow0 = brow + (wr << 7) + ((lane >> 4) << 2);
    const int cb0   = bcol + (wc << 6) + l15;
    const float bs0 = bias[cb0];
    const float bs1 = bias[cb0 + 16];
    const float bs2 = bias[cb0 + 32];
    const float bs3 = bias[cb0 + 48];
    const size_t P  = (size_t)B_ * H_;
#pragma unroll
    for (int mf = 0; mf < 8; ++mf) {
#pragma unroll
        for (int j = 0; j < 4; ++j) {
            const int row = crow0 + mf * 16 + j;
            const size_t base = (size_t)row * H_ + hcol;
            float fg = sigf(acc[mf][0][j] + bs0);
            float ig = sigf(acc[mf][1][j] + bs1);
            float kg = tanhfast(acc[mf][2][j] + bs2);
            float og = sigf(acc[mf][3][j] + bs3);
            float cv = c[base];
            float cn = fg * cv + ig * kg;
            float hn = og * tanhfast(cn);
            out[base]         = og;
            out[P + base]     = cn;
            out[2 * P + base] = hn;
        }
    }
}

// ---------------------------------------------------------------- launch
extern "C" void kernel_launch(void* const* d_in, const int* in_sizes, int n_in,
                              void* d_out, int out_size, void* d_ws, size_t ws_size,
                              hipStream_t stream)
{
    const float* x  = (const float*)d_in[0];
    const float* c  = (const float*)d_in[1];
    const float* h  = (const float*)d_in[2];
    const float* Wx = (const float*)d_in[3];
    const float* bx = (const float*)d_in[4];
    const float* Wh = (const float*)d_in[5];
    const float* bh = (const float*)d_in[6];

    unsigned short* Abf  = (unsigned short*)((char*)d_ws + OFF_A);
    unsigned short* Wbf  = (unsigned short*)((char*)d_ws + OFF_W);
    float*          bias = (float*)((char*)d_ws + OFF_BI);
    float*          out  = (float*)d_out;

    cvt_kernel<<<40960, 256, 0, stream>>>(x, h, Wx, Wh, Abf, Wbf);
    bias_kernel<<<16, 256, 0, stream>>>(bx, bh, bias);
    gemm_lstm<<<(M / 256) * (N / 256), 512, 0, stream>>>(
        Abf, Wbf, bias, c, out);
}

// Round 10
// 330.135 us; speedup vs baseline: 1.0967x; 1.0163x over previous
//
#include <hip/hip_runtime.h>
#include <hip/hip_bf16.h>
#include <cstdint>

#define DI __device__ __forceinline__

typedef __attribute__((ext_vector_type(4))) float f32x4;
typedef __attribute__((ext_vector_type(8))) short bf16x8;

static constexpr int B_ = 16384, I_ = 1024, H_ = 1024;
static constexpr int M = B_;          // 16384 rows
static constexpr int N = 4 * H_;      // 4096 gate-cols (permuted: see cvt)
static constexpr int K = I_ + H_;     // 2048 ([x | h])
static constexpr int NT = K / 64;     // 32 K-tiles

// workspace layout (bytes)
static constexpr size_t OFF_A  = 0;                         // M*K bf16   (64 MB)
static constexpr size_t OFF_W  = OFF_A + (size_t)M * K * 2; // N*K bf16   (16 MB)
static constexpr size_t OFF_BI = OFF_W + (size_t)N * K * 2; // N f32      (16 KB)

DI unsigned short f2bf(float f) {
    union { float f; unsigned u; } v; v.f = f;
    unsigned r = v.u + 0x7FFFu + ((v.u >> 16) & 1u);
    return (unsigned short)(r >> 16);
}

// ---------------------------------------------------------------- convert
// A' = [x | h] (M x K) bf16. W' rows PERMUTED so that GEMM col
// r = g64*64 + gate*16 + l15 maps to (gate, hcol = g64*16 + l15).
__global__ void cvt_kernel(const float* __restrict__ x, const float* __restrict__ h,
                           const float* __restrict__ Wx, const float* __restrict__ Wh,
                           unsigned short* __restrict__ A, unsigned short* __restrict__ W)
{
    long tid = (long)blockIdx.x * blockDim.x + threadIdx.x;
    long row = tid >> 9;
    int  col = (int)(tid & 511) * 4;
    const float* src;
    unsigned short* dst;
    if (row < M) {
        src = (col < I_) ? x + (size_t)row * I_ + col
                         : h + (size_t)row * H_ + (col - I_);
        dst = A + (size_t)row * K + col;
    } else {
        int r = (int)(row - M);                 // dst row in W'
        int gate = (r >> 4) & 3;
        int hcol = ((r >> 6) << 4) | (r & 15);
        int srow = gate * H_ + hcol;            // src row in [4,H] stack
        src = (col < I_) ? Wx + (size_t)srow * I_ + col
                         : Wh + (size_t)srow * H_ + (col - I_);
        dst = W + (size_t)r * K + col;
    }
    float4 v = *(const float4*)src;
    ushort4 o;
    o.x = f2bf(v.x); o.y = f2bf(v.y); o.z = f2bf(v.z); o.w = f2bf(v.w);
    *(ushort4*)dst = o;
}

__global__ void bias_kernel(const float* __restrict__ bx, const float* __restrict__ bh,
                            float* __restrict__ bias)
{
    int r = blockIdx.x * blockDim.x + threadIdx.x;
    if (r < N) {
        int gate = (r >> 4) & 3;
        int hcol = ((r >> 6) << 4) | (r & 15);
        int s = gate * H_ + hcol;
        bias[r] = bx[s] + bh[s];
    }
}

// ---------------------------------------------------------------- GEMM 256x256
// Round-9 body (one barrier per K-tile, compiler-scheduled tile body).
// NEW: L2-partitioned block mapping. Each XCD (bid&7) owns exactly 2 B-panels
// (nbk = xcd*2 + loc&1, 2 MB -> pinned in that XCD's 4 MB L2 for the whole
// kernel) and sweeps all 64 A-panels (mbk = loc>>1; consecutive concurrent
// blocks share the A-panel). Cuts logical L2-fill traffic from ~2 GB
// (A x16, B x64 redundant panel fetches -- the measured ~7 TB/s hierarchy
// saturation) to ~0.6 GB.
DI void stage_half(const unsigned short* __restrict__ g, int grow0, int kcol,
                   unsigned short* ldsbase, int tid)
{
    const int w    = tid >> 6, lane = tid & 63;
    const int rsub = (w << 3) + (lane >> 3);
    const int kk   = kcol + (((lane & 7) ^ (lane >> 3)) << 3);  // inverse-swizzled src
#pragma unroll
    for (int l = 0; l < 2; ++l) {
        const unsigned short* gp = g + (size_t)(grow0 + (l << 6) + rsub) * K + kk;
        unsigned short* lp = ldsbase + (((l << 6) + (w << 3)) << 6);
        __builtin_amdgcn_global_load_lds(
            (const __attribute__((address_space(1))) void*)gp,
            (__attribute__((address_space(3))) void*)lp, 16, 0, 0);
    }
}

DI bf16x8 ldfrag(const unsigned short* tile, int row, int ks, int lane)
{
    const int sl = ((ks << 2) + (lane >> 4)) ^ (lane & 7);
    return *(const bf16x8*)(tile + (row << 6) + (sl << 3));
}

DI float sigf(float v) { return 1.f / (1.f + __expf(-v)); }
DI float tanhfast(float v) {
    float vc = fminf(fmaxf(v, -15.f), 15.f);
    float e  = __expf(2.f * vc);
    return (e - 1.f) / (e + 1.f);
}

__global__ __launch_bounds__(512, 2) void gemm_lstm(
    const unsigned short* __restrict__ Abf, const unsigned short* __restrict__ Wbf,
    const float* __restrict__ bias, const float* __restrict__ c,
    float* __restrict__ out)
{
    __shared__ __align__(16) unsigned short sh[65536];   // 128 KiB

    const int tid  = threadIdx.x;
    const int lane = tid & 63;
    const int wid  = tid >> 6;
    const int wr   = wid >> 2;            // 0..1
    const int wc   = wid & 3;             // 0..3

    // L2-partitioned mapping: XCD = bid&7 (dispatch round-robin), owns
    // nbk in {2*xcd, 2*xcd+1}; mbk sweeps; local pairs share mbk.
    const int bid  = blockIdx.x;
    const int xcd  = bid & 7;
    const int loc  = bid >> 3;            // 0..127
    const int nbk  = (xcd << 1) | (loc & 1);   // 0..15
    const int mbk  = loc >> 1;                 // 0..63
    const int brow = mbk << 8, bcol = nbk << 8;

    const int l15  = lane & 15;
    const int rA0  = (wr << 7) + l15;
    const int rB0  = (wc << 6) + l15;

    f32x4 acc[8][4];
#pragma unroll
    for (int i = 0; i < 8; ++i)
#pragma unroll
        for (int j = 0; j < 4; ++j) acc[i][j] = f32x4{0.f, 0.f, 0.f, 0.f};
    bf16x8 a[4][2], b[4][2];

    // prologue: stage tile0, drain, publish
    {
        stage_half(Abf, brow,       0, sh,         tid);
        stage_half(Abf, brow + 128, 0, sh + 8192,  tid);
        stage_half(Wbf, bcol,       0, sh + 16384, tid);
        stage_half(Wbf, bcol + 128, 0, sh + 24576, tid);
        asm volatile("s_waitcnt vmcnt(0)" ::: "memory");
        __builtin_amdgcn_s_barrier();
    }

    for (int t = 0; t < NT; ++t) {
        const int q = t & 1;
        unsigned short* curA = sh + q * 32768;
        unsigned short* curB = curA + 16384;
        unsigned short* nxtA = sh + (q ^ 1) * 32768;
        unsigned short* nxtB = nxtA + 16384;
        const int k1 = ((t + 1) & 31) << 6;   // wrapped at tail: garbage into dead buf

        // stage entire tile t+1 (nxt last read in tile t-1, published free)
        stage_half(Abf, brow,       k1, nxtA,        tid);
        stage_half(Abf, brow + 128, k1, nxtA + 8192, tid);
        stage_half(Wbf, bcol,       k1, nxtB,        tid);
        stage_half(Wbf, bcol + 128, k1, nxtB + 8192, tid);

        // ---- B frags (8 reads) + A mh0 (8 reads)
#pragma unroll
        for (int n = 0; n < 4; ++n)
#pragma unroll
            for (int ks = 0; ks < 2; ++ks)
                b[n][ks] = ldfrag(curB, rB0 + n * 16, ks, lane);
#pragma unroll
        for (int m = 0; m < 4; ++m)
#pragma unroll
            for (int ks = 0; ks < 2; ++ks)
                a[m][ks] = ldfrag(curA, rA0 + m * 16, ks, lane);

        // ---- MFMA mh0 (32)
#pragma unroll
        for (int ks = 0; ks < 2; ++ks)
#pragma unroll
            for (int m = 0; m < 4; ++m)
#pragma unroll
                for (int n = 0; n < 4; ++n)
                    acc[m][n] = __builtin_amdgcn_mfma_f32_16x16x32_bf16(
                        a[m][ks], b[n][ks], acc[m][n], 0, 0, 0);

        // ---- A mh1 (8 reads, reuse a[] regs)
#pragma unroll
        for (int m = 0; m < 4; ++m)
#pragma unroll
            for (int ks = 0; ks < 2; ++ks)
                a[m][ks] = ldfrag(curA, rA0 + 64 + m * 16, ks, lane);

        // ---- MFMA mh1 (32)
#pragma unroll
        for (int ks = 0; ks < 2; ++ks)
#pragma unroll
            for (int m = 0; m < 4; ++m)
#pragma unroll
                for (int n = 0; n < 4; ++n)
                    acc[4 + m][n] = __builtin_amdgcn_mfma_f32_16x16x32_bf16(
                        a[m][ks], b[n][ks], acc[4 + m][n], 0, 0, 0);

        // tile-end: publish tile t+1 and release cur
        asm volatile("s_waitcnt vmcnt(0)" ::: "memory");
        __builtin_amdgcn_s_barrier();
    }

    // ---- fused LSTM epilogue: n-index = gate for one h-col per lane
    const int hcol  = (((nbk << 2) + wc) << 4) + l15;
    const int crow0 = brow + (wr << 7) + ((lane >> 4) << 2);
    const int cb0   = bcol + (wc << 6) + l15;
    const float bs0 = bias[cb0];
    const float bs1 = bias[cb0 + 16];
    const float bs2 = bias[cb0 + 32];
    const float bs3 = bias[cb0 + 48];
    const size_t P  = (size_t)B_ * H_;
#pragma unroll
    for (int mf = 0; mf < 8; ++mf) {
#pragma unroll
        for (int j = 0; j < 4; ++j) {
            const int row = crow0 + mf * 16 + j;
            const size_t base = (size_t)row * H_ + hcol;
            float fg = sigf(acc[mf][0][j] + bs0);
            float ig = sigf(acc[mf][1][j] + bs1);
            float kg = tanhfast(acc[mf][2][j] + bs2);
            float og = sigf(acc[mf][3][j] + bs3);
            float cv = c[base];
            float cn = fg * cv + ig * kg;
            float hn = og * tanhfast(cn);
            out[base]         = og;
            out[P + base]     = cn;
            out[2 * P + base] = hn;
        }
    }
}

// ---------------------------------------------------------------- launch
extern "C" void kernel_launch(void* const* d_in, const int* in_sizes, int n_in,
                              void* d_out, int out_size, void* d_ws, size_t ws_size,
                              hipStream_t stream)
{
    const float* x  = (const float*)d_in[0];
    const float* c  = (const float*)d_in[1];
    const float* h  = (const float*)d_in[2];
    const float* Wx = (const float*)d_in[3];
    const float* bx = (const float*)d_in[4];
    const float* Wh = (const float*)d_in[5];
    const float* bh = (const float*)d_in[6];

    unsigned short* Abf  = (unsigned short*)((char*)d_ws + OFF_A);
    unsigned short* Wbf  = (unsigned short*)((char*)d_ws + OFF_W);
    float*          bias = (float*)((char*)d_ws + OFF_BI);
    float*          out  = (float*)d_out;

    cvt_kernel<<<40960, 256, 0, stream>>>(x, h, Wx, Wh, Abf, Wbf);
    bias_kernel<<<16, 256, 0, stream>>>(bx, bh, bias);
    gemm_lstm<<<(M / 256) * (N / 256), 512, 0, stream>>>(
        Abf, Wbf, bias, c, out);
}